// Round 4
// baseline (1643.401 us; speedup 1.0000x reference)
//
#include <hip/hip_runtime.h>
#include <hip/hip_bf16.h>
#include <cstddef>

#define N_NODES 16000
#define N_EDGES 256000
#define DIM 256
#define HEADS 8
#define DFF 1024
#define LN_EPS 1e-5f
#define CNT ((float)((size_t)N_NODES * DIM))
#define RSDH 0.17677669529663687f

typedef __attribute__((ext_vector_type(8))) short short8;
typedef __attribute__((ext_vector_type(4))) float floatx4;

__device__ __forceinline__ float bf2f(unsigned int s) {
    return __uint_as_float(s << 16);
}

__device__ __forceinline__ float2 ln_ms(const float* __restrict__ s) {
    float mu = s[0] * (1.0f / CNT);
    float var = s[1] * (1.0f / CNT) - mu * mu;
    float2 r; r.x = mu; r.y = 1.0f / (sqrtf(fmaxf(var, 0.0f)) + LN_EPS);
    return r;
}

// async global->LDS, 16B per lane (global_load_lds_dwordx4)
__device__ __forceinline__ void async16(const __hip_bfloat16* g, __hip_bfloat16* l) {
    __builtin_amdgcn_global_load_lds(
        (const __attribute__((address_space(1))) void*)g,
        (__attribute__((address_space(3))) void*)l, 16, 0, 0);
}

__device__ __forceinline__ void pack8(__hip_bfloat16* d, float4 a, float4 b) {
    union { short8 f; __hip_bfloat16 h[8]; } u;
    u.h[0] = __float2bfloat16(a.x); u.h[1] = __float2bfloat16(a.y);
    u.h[2] = __float2bfloat16(a.z); u.h[3] = __float2bfloat16(a.w);
    u.h[4] = __float2bfloat16(b.x); u.h[5] = __float2bfloat16(b.y);
    u.h[6] = __float2bfloat16(b.z); u.h[7] = __float2bfloat16(b.w);
    *(short8*)d = u.f;
}

__device__ __forceinline__ float4 lnaff(float4 v, float4 g, float4 b, float mu, float sc) {
    v.x = (v.x - mu) * sc * g.x + b.x;
    v.y = (v.y - mu) * sc * g.y + b.y;
    v.z = (v.z - mu) * sc * g.z + b.z;
    v.w = (v.w - mu) * sc * g.w + b.w;
    return v;
}

// ---------------- bf16 MFMA GEMM: C[M,N] = A[M,K] @ Bt[N,K]^T ----------------
// TM=128: 128x128 tile, 4 waves x (4x4) frags. TM=64: 64x128, 4 waves x (4x2).
// ACVT: A fp32, converted during staging (optional LN affine on read, lnA_*).
// RES:  residual read (optional LN affine on read, lnR_*).
// OBF16: 0 = fp32 out, 1 = bf16 out,
//        3 = dual: cols<512 -> fp32 to C (stride 512); cols>=512 -> bf16
//            K|V 4-chunk interleave to C2 (stride 512). Branch uniform/block.
// ostats: if non-null, block-reduced sum/sumsq of outputs -> atomicAdd.
template<int BIAS, int RELU, int RES, int OBF16, int ACVT, int TM>
__global__ __launch_bounds__(256) void mgemm_k(
    const void* __restrict__ Ap, const __hip_bfloat16* __restrict__ Bt,
    const float* __restrict__ bias, const float* __restrict__ res,
    void* __restrict__ C, void* __restrict__ C2, int M, int K, int N,
    const float* __restrict__ lnA_s, const float* __restrict__ lnA_g,
    const float* __restrict__ lnA_b,
    const float* __restrict__ lnR_s, const float* __restrict__ lnR_g,
    const float* __restrict__ lnR_b,
    float* __restrict__ ostats)
{
    __shared__ __hip_bfloat16 As[TM * 32];    // [m][k] row-major
    __shared__ __hip_bfloat16 Bs[128 * 32];   // [n][k] row-major, 8 KB
    __shared__ float rs[8];
    const int tid = threadIdx.x;
    const int lane = tid & 63, wv = tid >> 6;
    const int wm = (TM == 128) ? (wv & 1) * 64 : 0;
    const int wn = (TM == 128) ? (wv >> 1) * 64 : wv * 32;
    const int NJ = (TM == 128) ? 4 : 2;       // column frags per wave
    const int row0 = blockIdx.y * TM, col0 = blockIdx.x * 128;
    const int lr = tid >> 2;            // 0..63: tile row
    const int lk = (tid & 3) * 8;       // k offset 0/8/16/24

    float muA = 0.0f, scA = 1.0f;
    if (ACVT && lnA_s) { float2 t = ln_ms(lnA_s); muA = t.x; scA = t.y; }

    floatx4 acc[4][4];
    const floatx4 zf = {0.f, 0.f, 0.f, 0.f};
    #pragma unroll
    for (int i = 0; i < 4; i++)
        #pragma unroll
        for (int j = 0; j < 4; j++) acc[i][j] = zf;

    const int a_fo = (wm + (lane & 15)) * 32 + (lane >> 4) * 8;
    const int b_fo = (wn + (lane & 15)) * 32 + (lane >> 4) * 8;

    for (int k0 = 0; k0 < K; k0 += 32) {
        if (ACVT) {
            const float* A = (const float*)Ap;
            const float* p0 = A + (size_t)(row0 + lr) * K + k0 + lk;
            float4 v0 = *(const float4*)(p0);
            float4 v1 = *(const float4*)(p0 + 4);
            if (lnA_s) {
                float4 ga = *(const float4*)(lnA_g + k0 + lk);
                float4 gb = *(const float4*)(lnA_g + k0 + lk + 4);
                float4 ba = *(const float4*)(lnA_b + k0 + lk);
                float4 bb = *(const float4*)(lnA_b + k0 + lk + 4);
                v0 = lnaff(v0, ga, ba, muA, scA);
                v1 = lnaff(v1, gb, bb, muA, scA);
                if (TM == 128) {
                    const float* p1 = A + (size_t)(row0 + lr + 64) * K + k0 + lk;
                    float4 w0 = lnaff(*(const float4*)(p1), ga, ba, muA, scA);
                    float4 w1 = lnaff(*(const float4*)(p1 + 4), gb, bb, muA, scA);
                    pack8(As + 2048 + tid * 8, w0, w1);
                }
            } else if (TM == 128) {
                const float* p1 = A + (size_t)(row0 + lr + 64) * K + k0 + lk;
                pack8(As + 2048 + tid * 8, *(const float4*)(p1), *(const float4*)(p1 + 4));
            }
            pack8(As + tid * 8, v0, v1);
        } else {
            const __hip_bfloat16* A = (const __hip_bfloat16*)Ap;
            async16(A + (size_t)(row0 + lr) * K + k0 + lk, As + tid * 8);
            if (TM == 128)
                async16(A + (size_t)(row0 + lr + 64) * K + k0 + lk, As + 2048 + tid * 8);
        }
        async16(Bt + (size_t)(col0 + lr) * K + k0 + lk, Bs + tid * 8);
        async16(Bt + (size_t)(col0 + lr + 64) * K + k0 + lk, Bs + 2048 + tid * 8);
        __syncthreads();
        short8 a[4], b[4];
        #pragma unroll
        for (int i = 0; i < 4; i++)
            a[i] = *(const short8*)(As + a_fo + i * 16 * 32);
        #pragma unroll
        for (int j = 0; j < NJ; j++)
            b[j] = *(const short8*)(Bs + b_fo + j * 16 * 32);
        #pragma unroll
        for (int i = 0; i < 4; i++)
            #pragma unroll
            for (int j = 0; j < NJ; j++)
                acc[i][j] = __builtin_amdgcn_mfma_f32_16x16x32_bf16(a[i], b[j], acc[i][j], 0, 0, 0);
        __syncthreads();
    }
    // epilogue: D[m=(lane>>4)*4+r][n=lane&15] per 16x16 tile
    float muR = 0.0f, scR = 1.0f;
    if (RES && lnR_s) { float2 t = ln_ms(lnR_s); muR = t.x; scR = t.y; }
    const int rbase = row0 + wm + (lane >> 4) * 4;
    const int cbase = col0 + wn + (lane & 15);
    float s1 = 0.0f, s2 = 0.0f;
    #pragma unroll
    for (int j = 0; j < NJ; j++) {
        const int c = cbase + j * 16;
        float bb = BIAS ? bias[c] : 0.0f;
        float gr = (RES && lnR_s) ? lnR_g[c] : 1.0f;
        float br = (RES && lnR_s) ? lnR_b[c] : 0.0f;
        #pragma unroll
        for (int i = 0; i < 4; i++) {
            #pragma unroll
            for (int r = 0; r < 4; r++) {
                const int rr = rbase + i * 16 + r;
                float v = acc[i][j][r] + bb;
                if (RELU) v = fmaxf(v, 0.0f);
                if (RES) {
                    float rv = res[(size_t)rr * N + c];
                    if (lnR_s) rv = (rv - muR) * scR * gr + br;
                    v += rv;
                }
                if (ostats) { s1 += v; s2 += v * v; }
                if (OBF16 == 3) {
                    if (c < 512) {
                        ((float*)C)[(size_t)rr * 512 + c] = v;
                    } else {
                        const int cc = c - 512;
                        const int ccc = cc & 255;
                        const int idx = ((ccc >> 2) << 3) + (ccc & 3) + ((cc >> 8) << 2);
                        ((__hip_bfloat16*)C2)[(size_t)rr * 512 + idx] = __float2bfloat16(v);
                    }
                } else if (OBF16 == 1) {
                    ((__hip_bfloat16*)C)[(size_t)rr * N + c] = __float2bfloat16(v);
                } else {
                    ((float*)C)[(size_t)rr * N + c] = v;
                }
            }
        }
    }
    if (ostats) {
        #pragma unroll
        for (int o = 32; o > 0; o >>= 1) {
            s1 += __shfl_down(s1, o);
            s2 += __shfl_down(s2, o);
        }
        if (lane == 0) { rs[wv] = s1; rs[4 + wv] = s2; }
        __syncthreads();
        if (tid == 0) {
            atomicAdd(&ostats[0], rs[0] + rs[1] + rs[2] + rs[3]);
            atomicAdd(&ostats[1], rs[4] + rs[5] + rs[6] + rs[7]);
        }
    }
}

// ---------------- weight transpose + bf16 convert: dst[C][R] = src[R][C] -------
// batched over blockIdx.z with independent src/dst strides
__global__ __launch_bounds__(256) void tcvt_k(const float* __restrict__ src,
                                              __hip_bfloat16* __restrict__ dst,
                                              int R, int C, int sStride, int dStride)
{
    src += (size_t)blockIdx.z * sStride;
    dst += (size_t)blockIdx.z * dStride;
    __shared__ float t[32][33];
    const int c0 = blockIdx.x * 32, r0 = blockIdx.y * 32;
    const int tx = threadIdx.x & 31, ty = threadIdx.x >> 5;   // 32 x 8
    #pragma unroll
    for (int j = 0; j < 32; j += 8)
        t[ty + j][tx] = src[(size_t)(r0 + ty + j) * C + c0 + tx];
    __syncthreads();
    #pragma unroll
    for (int j = 0; j < 32; j += 8)
        dst[(size_t)(c0 + ty + j) * R + r0 + tx] = __float2bfloat16(t[tx][ty + j]);
}

// concat 4x256 biases -> [a|b|c|d] per transformer block (blockIdx.y)
__global__ __launch_bounds__(256) void bcat_k(const float* __restrict__ ba,
                                              const float* __restrict__ bb,
                                              const float* __restrict__ bc,
                                              const float* __restrict__ bd,
                                              float* __restrict__ o)
{
    const int z = blockIdx.y;
    int t = blockIdx.x * 256 + threadIdx.x;   // 1024
    float v = (t < 256) ? ba[z * 256 + t] : (t < 512) ? bb[z * 256 + t - 256]
            : (t < 768) ? bc[z * 256 + t - 512] : bd[z * 256 + t - 768];
    o[(size_t)z * 1024 + t] = v;
}

// ---------------- CSR build ----------------
__global__ __launch_bounds__(256) void hist_k(const int* __restrict__ dst, int* __restrict__ deg)
{
    int e = blockIdx.x * blockDim.x + threadIdx.x;
    if (e < N_EDGES) atomicAdd(&deg[dst[e]], 1);
}

__global__ __launch_bounds__(1024) void scan_k(const int* __restrict__ deg,
                                               int* __restrict__ rowptr,
                                               int* __restrict__ cursor)
{
    __shared__ int wsum[16];
    const int t = threadIdx.x;          // 16000 = 1000 threads x 16
    const int base = t * 16;
    int local[16];
    int s = 0;
    if (t < 1000) {
        #pragma unroll
        for (int j = 0; j < 16; j++) { local[j] = s; s += deg[base + j]; }
    }
    const int lane = t & 63, w = t >> 6;
    int v = s;
    #pragma unroll
    for (int off = 1; off < 64; off <<= 1) {
        int u = __shfl_up(v, off);
        if (lane >= off) v += u;
    }
    if (lane == 63) wsum[w] = v;
    __syncthreads();
    if (t == 0) {
        int r = 0;
        #pragma unroll
        for (int i = 0; i < 16; i++) { int u = wsum[i]; wsum[i] = r; r += u; }
    }
    __syncthreads();
    const int excl = v - s + wsum[w];
    if (t < 1000) {
        #pragma unroll
        for (int j = 0; j < 16; j++) {
            rowptr[base + j] = excl + local[j];
            cursor[base + j] = excl + local[j];
        }
        if (t == 999) rowptr[16000] = excl + s;
    }
}

// scatter: also emit src and logit scale in CSR-permuted order
__global__ __launch_bounds__(256) void scatter_k(const int* __restrict__ dst,
                                                 const int* __restrict__ src,
                                                 const float* __restrict__ xd,
                                                 int* __restrict__ cursor,
                                                 int* __restrict__ eperm,
                                                 int* __restrict__ srcp,
                                                 float* __restrict__ scale)
{
    int e = blockIdx.x * blockDim.x + threadIdx.x;
    if (e < N_EDGES) {
        int pos = atomicAdd(&cursor[dst[e]], 1);
        eperm[pos] = e;
        srcp[pos] = src[e];
        scale[pos] = RSDH / xd[e];
    }
}

// gather x_edge rows into CSR order, bf16 (once per launch)
__global__ __launch_bounds__(256) void eprep_k(const float* __restrict__ xe,
                                               const int* __restrict__ eperm,
                                               __hip_bfloat16* __restrict__ xeb)
{
    const int r = blockIdx.x * 4 + (threadIdx.x >> 6);
    const int lane = threadIdx.x & 63;
    const int e = eperm[r];
    float4 v = *(const float4*)(xe + (size_t)e * DIM + lane * 4);
    union { short4 s; __hip_bfloat16 h[4]; } u;
    u.h[0] = __float2bfloat16(v.x); u.h[1] = __float2bfloat16(v.y);
    u.h[2] = __float2bfloat16(v.z); u.h[3] = __float2bfloat16(v.w);
    *(short4*)(xeb + (size_t)r * DIM + lane * 4) = u.s;
}

// ------- fused edge-projection + per-node attention aggregation ---------------
// Block = 8 nodes (8 waves, one node/wave); its CSR edge range is contiguous.
// Per 64-edge chunk:
//   1) stage xeb rows -> LDS via global_load_lds, XOR-swizzled SOURCE so the
//      MFMA a-read (stride-512B, else 16-way bank conflict) is conflict-free
//   2) E = xeb_chunk @ We^T via MFMA; B-frags read directly from global WeT
//      (128 KB, L2-resident) -> no B staging, no per-k barriers
//   3) write E (bf16) into the SAME LDS buffer (barrier-separated; 32 KB total)
//   4) per-wave attention over its node's edges in the chunk (e from LDS)
// kvb gather unchanged (bf16 K|V 4-chunk interleave, one 16B load/lane/edge).
// Fused: x-residual (optional LN-on-read) + skip + LN1 stats.
__global__ __launch_bounds__(512) void nagg_f_k(
    const float* __restrict__ qs, const __hip_bfloat16* __restrict__ kvb,
    const __hip_bfloat16* __restrict__ xeb, const __hip_bfloat16* __restrict__ WeT,
    const int* __restrict__ srcp, const float* __restrict__ scale,
    const int* __restrict__ rowptr,
    const float* __restrict__ xsrc, const float* __restrict__ lnx_s,
    const float* __restrict__ lnx_g, const float* __restrict__ lnx_b,
    float* __restrict__ y, float* __restrict__ ostats)
{
    __shared__ __hip_bfloat16 Axe[64 * 256];   // 32 KB; xeb chunk, then E chunk
    __shared__ float rs[16];
    const int tid = threadIdx.x, lane = tid & 63, wv = tid >> 6;  // 8 waves
    const int n0 = blockIdx.x * 8;
    const int nn = n0 + wv;                     // this wave's node
    const int e0 = rowptr[n0], eT = rowptr[n0 + 8];
    const int begw = rowptr[nn], endw = rowptr[nn + 1];
    const float4 q = *(const float4*)(qs + (size_t)nn * 512 + lane * 4);
    float a0 = 0, a1 = 0, a2 = 0, a3 = 0, den = 0;
    // B-frag base for this lane: n = wv*32 + j*16 + (lane&15), k-slot (lane>>4)*8
    const __hip_bfloat16* wb0 = WeT + (size_t)(wv * 32 + (lane & 15)) * 256 + (lane >> 4) * 8;

    for (int c0 = e0; c0 < eT; c0 += 64) {
        // ---- 1) stage xeb rows c0..c0+63 (clamped), swizzled source:
        // LDS[m][slot] = xeb[row(m)][slot ^ (m&7)]  (16B slot units)
        #pragma unroll
        for (int j = 0; j < 4; j++) {
            const int cid = tid + 512 * j;          // 0..2047
            const int m = cid >> 5;                 // 0..63
            const int sl = (cid & 31) ^ (m & 7);
            const int row = min(c0 + m, eT - 1);
            async16(xeb + (size_t)row * 256 + sl * 8, Axe + cid * 8);
        }
        __syncthreads();                            // drains the async copies
        // ---- 2) E = Axe @ WeT^T: wave-tile M=64 x N=32, K=256
        floatx4 ea[4][2];
        const floatx4 zf = {0.f, 0.f, 0.f, 0.f};
        #pragma unroll
        for (int i = 0; i < 4; i++) { ea[i][0] = zf; ea[i][1] = zf; }
        for (int k0 = 0; k0 < 256; k0 += 32) {
            short8 a[4], b[2];
            #pragma unroll
            for (int i = 0; i < 4; i++) {
                const int m = (lane & 15) + 16 * i;
                a[i] = *(const short8*)(Axe + m * 256 +
                        ((((k0 >> 3) + (lane >> 4)) ^ (m & 7)) << 3));
            }
            #pragma unroll
            for (int j = 0; j < 2; j++)
                b[j] = *(const short8*)(wb0 + j * 4096 + k0);
            #pragma unroll
            for (int i = 0; i < 4; i++)
                #pragma unroll
                for (int j = 0; j < 2; j++)
                    ea[i][j] = __builtin_amdgcn_mfma_f32_16x16x32_bf16(a[i], b[j], ea[i][j], 0, 0, 0);
        }
        __syncthreads();                            // all Axe reads done
        // ---- 3) E -> LDS (bf16), row-swizzled: byte = m*512 + (col*2 ^ ((m&7)<<4))
        #pragma unroll
        for (int i = 0; i < 4; i++)
            #pragma unroll
            for (int j = 0; j < 2; j++)
                #pragma unroll
                for (int r = 0; r < 4; r++) {
                    const int m = i * 16 + (lane >> 4) * 4 + r;
                    const int col = wv * 32 + j * 16 + (lane & 15);
                    *(__hip_bfloat16*)((char*)Axe + m * 512 + ((col * 2) ^ ((m & 7) << 4))) =
                        __float2bfloat16(ea[i][j][r]);
                }
        __syncthreads();                            // E chunk ready
        // ---- 4) aggregate this wave's edges within [c0, c0+64)
        const int lo = max(begw, c0), hi = min(endw, c0 + 64);
        int s = (lo < hi) ? srcp[lo] : 0;
        for (int idx = lo; idx < hi; idx++) {
            const int scur = s;
            if (idx + 1 < hi) s = srcp[idx + 1];
            const float sc = scale[idx];
            const uint4 kv = *(const uint4*)(kvb + (size_t)scur * 512 + lane * 8);
            const int el = idx - c0;
            const uint2 eb = *(const uint2*)((const char*)Axe + el * 512 +
                                             ((lane * 8) ^ ((el & 7) << 4)));
            const float e0v = bf2f(eb.x & 0xffffu), e1v = bf2f(eb.x >> 16);
            const float e2v = bf2f(eb.y & 0xffffu), e3v = bf2f(eb.y >> 16);
            float part = q.x * (bf2f(kv.x & 0xffffu) + e0v)
                       + q.y * (bf2f(kv.x >> 16) + e1v)
                       + q.z * (bf2f(kv.y & 0xffffu) + e2v)
                       + q.w * (bf2f(kv.y >> 16) + e3v);
            part += __shfl_xor(part, 1);
            part += __shfl_xor(part, 2);
            part += __shfl_xor(part, 4);   // 8 lanes of this head share the dot
            const float ex = __expf(part * sc);
            den += ex;
            a0 = fmaf(bf2f(kv.z & 0xffffu) + e0v, ex, a0);
            a1 = fmaf(bf2f(kv.z >> 16) + e1v, ex, a1);
            a2 = fmaf(bf2f(kv.w & 0xffffu) + e2v, ex, a2);
            a3 = fmaf(bf2f(kv.w >> 16) + e3v, ex, a3);
        }
        __syncthreads();                            // chunk fully consumed
    }
    // ---- epilogue: residual + skip + LN1 stats
    const float dn = 1.0f / (den + 1e-16f);
    const size_t o = (size_t)nn * DIM + lane * 4;
    float4 xr = *(const float4*)(xsrc + o);
    if (lnx_s) {
        float2 t = ln_ms(lnx_s);
        const float4 g4 = *(const float4*)(lnx_g + lane * 4);
        const float4 b4 = *(const float4*)(lnx_b + lane * 4);
        xr = lnaff(xr, g4, b4, t.x, t.y);
    }
    const float4 sr = *(const float4*)(qs + (size_t)nn * 512 + 256 + lane * 4);
    float4 out;
    out.x = xr.x + a0 * dn + sr.x;
    out.y = xr.y + a1 * dn + sr.y;
    out.z = xr.z + a2 * dn + sr.z;
    out.w = xr.w + a3 * dn + sr.w;
    *(float4*)(y + o) = out;
    float s1 = out.x + out.y + out.z + out.w;
    float s2 = out.x * out.x + out.y * out.y + out.z * out.z + out.w * out.w;
    #pragma unroll
    for (int of = 32; of > 0; of >>= 1) {
        s1 += __shfl_down(s1, of);
        s2 += __shfl_down(s2, of);
    }
    if (lane == 0) { rs[wv] = s1; rs[8 + wv] = s2; }
    __syncthreads();
    if (tid == 0) {
        atomicAdd(&ostats[0], rs[0] + rs[1] + rs[2] + rs[3] + rs[4] + rs[5] + rs[6] + rs[7]);
        atomicAdd(&ostats[1], rs[8] + rs[9] + rs[10] + rs[11] + rs[12] + rs[13] + rs[14] + rs[15]);
    }
}

// ---------------- final LN apply (only for d_out) ----------------
__global__ __launch_bounds__(256) void apply_k(
    const float* __restrict__ y, const float* __restrict__ stats,
    const float* __restrict__ g, const float* __restrict__ b,
    float* __restrict__ xo)
{
    int idx = blockIdx.x * blockDim.x + threadIdx.x;  // float4 index
    float2 t = ln_ms(stats);
    int cb = (idx & 63) * 4;
    float4 v  = *(const float4*)(y + (size_t)idx * 4);
    float4 gv = *(const float4*)(g + cb);
    float4 bv = *(const float4*)(b + cb);
    *(float4*)(xo + (size_t)idx * 4) = lnaff(v, gv, bv, t.x, t.y);
}

extern "C" void kernel_launch(void* const* d_in, const int* in_sizes, int n_in,
                              void* d_out, int out_size, void* d_ws, size_t ws_size,
                              hipStream_t stream) {
    const float* x_in   = (const float*)d_in[0];
    const int*   ei     = (const int*)d_in[1];
    const int*   src    = ei;                 // edge_index[0]
    const int*   dstp   = ei + N_EDGES;       // edge_index[1]
    const float* x_edge = (const float*)d_in[2];
    const float* x_dist = (const float*)d_in[3];
    const float* Wq  = (const float*)d_in[4];
    const float* bq  = (const float*)d_in[5];
    const float* Wk  = (const float*)d_in[6];
    const float* bk  = (const float*)d_in[7];
    const float* Wv  = (const float*)d_in[8];
    const float* bv  = (const float*)d_in[9];
    const float* We  = (const float*)d_in[10];
    const float* Wsk = (const float*)d_in[11];
    const float* bsk = (const float*)d_in[12];
    const float* g1  = (const float*)d_in[13];
    const float* b1  = (const float*)d_in[14];
    const float* W1  = (const float*)d_in[15];
    const float* c1  = (const float*)d_in[16];
    const float* W2  = (const float*)d_in[17];
    const float* c2  = (const float*)d_in[18];
    const float* g2  = (const float*)d_in[19];
    const float* b2  = (const float*)d_in[20];

    // ---- workspace carve ----
    char* p = (char*)d_ws;
    float* ybuf = (float*)p; p += (size_t)N_NODES * DIM * sizeof(float);           // 16.4 MB
    float* qsb  = (float*)p; p += (size_t)N_NODES * 512 * sizeof(float);           // 32.8 MB  [Q|S] fp32
    __hip_bfloat16* kvb = (__hip_bfloat16*)p; p += (size_t)N_NODES * 512 * 2;      // 16.4 MB  [K|V] bf16 interleaved
    __hip_bfloat16* hb16 = (__hip_bfloat16*)p; p += (size_t)N_NODES * 1024 * 2;    // 32.8 MB
    __hip_bfloat16* xeb  = (__hip_bfloat16*)p; p += (size_t)N_EDGES * DIM * 2;     // 131 MB
    __hip_bfloat16* WqkvsT = (__hip_bfloat16*)p; p += (size_t)3 * 1024 * 256 * 2;  // [Wq|Wsk|Wk|Wv]^T
    __hip_bfloat16* WeT    = (__hip_bfloat16*)p; p += (size_t)3 * 256 * 256 * 2;
    __hip_bfloat16* W1T    = (__hip_bfloat16*)p; p += (size_t)3 * 1024 * 256 * 2;
    __hip_bfloat16* W2T    = (__hip_bfloat16*)p; p += (size_t)3 * 256 * 1024 * 2;
    float* bqkvs = (float*)p; p += (size_t)3 * 1024 * sizeof(float);               // [bq|bsk|bk|bv]
    float* stats = (float*)p;  p += 64;                       // [block][ln1_s,ln1_ss,ln2_s,ln2_ss]
    int* deg     = (int*)p;    p += (size_t)N_NODES * sizeof(int);
    int* rowptr  = (int*)p;    p += (size_t)(N_NODES + 4) * sizeof(int);
    int* cursor  = (int*)p;    p += (size_t)N_NODES * sizeof(int);
    int* eperm   = (int*)p;    p += (size_t)N_EDGES * sizeof(int);
    int* srcp    = (int*)p;    p += (size_t)N_EDGES * sizeof(int);
    float* scale = (float*)p;  p += (size_t)N_EDGES * sizeof(float);

    const dim3 blk(256);

    // ---- CSR build (edge list constant across blocks) ----
    hipMemsetAsync(deg, 0, (size_t)N_NODES * sizeof(int), stream);
    hipMemsetAsync(stats, 0, 48, stream);
    hist_k<<<N_EDGES / 256, blk, 0, stream>>>(dstp, deg);
    scan_k<<<1, 1024, 0, stream>>>(deg, rowptr, cursor);
    scatter_k<<<N_EDGES / 256, blk, 0, stream>>>(dstp, src, x_dist, cursor, eperm, srcp, scale);
    eprep_k<<<N_EDGES / 4, blk, 0, stream>>>(x_edge, eperm, xeb);

    // ---- weight prep: transpose + bf16 convert, order [Q|S|K|V], batched z=3 ----
    tcvt_k<<<dim3(8, 8, 3), blk, 0, stream>>>(Wq,  WqkvsT + 0 * 65536, 256, 256, 65536, 262144);
    tcvt_k<<<dim3(8, 8, 3), blk, 0, stream>>>(Wsk, WqkvsT + 1 * 65536, 256, 256, 65536, 262144);
    tcvt_k<<<dim3(8, 8, 3), blk, 0, stream>>>(Wk,  WqkvsT + 2 * 65536, 256, 256, 65536, 262144);
    tcvt_k<<<dim3(8, 8, 3), blk, 0, stream>>>(Wv,  WqkvsT + 3 * 65536, 256, 256, 65536, 262144);
    tcvt_k<<<dim3(8, 8, 3), blk, 0, stream>>>(We,  WeT, 256, 256, 65536, 65536);
    tcvt_k<<<dim3(32, 8, 3), blk, 0, stream>>>(W1, W1T, 256, 1024, 262144, 262144);
    tcvt_k<<<dim3(8, 32, 3), blk, 0, stream>>>(W2, W2T, 1024, 256, 262144, 262144);
    bcat_k<<<dim3(4, 3), blk, 0, stream>>>(bq, bsk, bk, bv, bqkvs);

    for (int i = 0; i < 3; i++) {
        const size_t bo = (size_t)i * DIM;
        const size_t b1o = (size_t)i * DFF;
        float* ln1 = stats + (size_t)i * 4;
        float* ln2 = stats + (size_t)i * 4 + 2;
        // LN2 of previous block, applied on-read to x
        const float* pls = (i == 0) ? nullptr : stats + (size_t)(i - 1) * 4 + 2;
        const float* plg = (i == 0) ? nullptr : g2 + (size_t)(i - 1) * 256;
        const float* plb = (i == 0) ? nullptr : b2 + (size_t)(i - 1) * 256;
        const float* xsrc = (i == 0) ? x_in : ybuf;

        // fused Q|S|K|V projection: LN(x) [16000,256] x [256,1024]
        // cols 0-511 -> qsb fp32; cols 512-1023 -> kvb bf16 interleaved
        mgemm_k<1,0,0,3,1,128><<<dim3(8, 125), blk, 0, stream>>>(
            xsrc, WqkvsT + (size_t)i * 262144, bqkvs + (size_t)i * 1024, nullptr,
            qsb, kvb, N_NODES, DIM, 1024, pls, plg, plb, nullptr, nullptr, nullptr, nullptr);
        // fused edge-projection + attention aggregation + residual + skip + LN1
        nagg_f_k<<<N_NODES / 8, dim3(512), 0, stream>>>(
            qsb, kvb, xeb, WeT + (size_t)i * 65536, srcp, scale, rowptr,
            xsrc, pls, plg, plb, ybuf, ln1);
        // FFN1: LN1(y) x W1 + bias + relu -> bf16
        mgemm_k<1,1,0,1,1,128><<<dim3(8, 125), blk, 0, stream>>>(
            ybuf, W1T + (size_t)i * 262144, c1 + b1o, nullptr,
            hb16, nullptr, N_NODES, DIM, DFF, ln1, g1 + bo, b1 + bo, nullptr, nullptr, nullptr, nullptr);
        // FFN2: h x W2 + bias + LN1(y) residual -> ybuf (in-place) + LN2 stats
        // TM=64: grid (2,250)=500 blocks -> 2 blocks/CU
        mgemm_k<1,0,1,0,0,64><<<dim3(2, 250), blk, 0, stream>>>(
            hb16, W2T + (size_t)i * 262144, c2 + bo, ybuf,
            ybuf, nullptr, N_NODES, DFF, DIM, nullptr, nullptr, nullptr, ln1, g1 + bo, b1 + bo, ln2);
        if (i == 2)
            apply_k<<<(N_NODES * DIM) / 1024, blk, 0, stream>>>(
                ybuf, ln2, g2 + bo, b2 + bo, (float*)d_out);
    }
}